// Round 12
// baseline (277.863 us; speedup 1.0000x reference)
//
#include <hip/hip_runtime.h>
#include <hip/hip_bf16.h>

// Problem constants (from reference)
#define BATCH_N   16384
#define FEAT      128      // MOVIE_FEAT == USER_FEAT
#define NNBR      50
#define NUM_MOVIES_N 100000

typedef short  short8  __attribute__((ext_vector_type(8)));
typedef float  floatx4 __attribute__((ext_vector_type(4)));
typedef unsigned int u32;

__device__ __forceinline__ __hip_bfloat16 f2bf(float x) { return __float2bfloat16(x); }
__device__ __forceinline__ float bfb2f(short s) {
  union { u32 u; float f; } c; c.u = ((u32)(unsigned short)s) << 16; return c.f;
}

// async global->LDS 16B DMA. LDS dst must be wave-uniform base + lane*16
// (m104), so the XOR swizzle is applied to the SOURCE index.
__device__ __forceinline__ void gld16(const __hip_bfloat16* g, __hip_bfloat16* l) {
  __builtin_amdgcn_global_load_lds(
      (const __attribute__((address_space(1))) u32*)g,
      (__attribute__((address_space(3))) u32*)l, 16, 0, 0);
}

__device__ __forceinline__ floatx4 mfma16(short8 a, short8 b, floatx4 c) {
  return __builtin_amdgcn_mfma_f32_16x16x32_bf16(a, b, c, 0, 0, 0);
}

// ---------------------------------------------------------------------------
// prep_all: fused (a) fp32 movie_table -> bf16 copy and (b) bf16 transposed
// weights Wt[n][k] + fused bias bu+bm. One launch.
// blocks [0,6250): conv;  [6250,6506): weight prep.
// ---------------------------------------------------------------------------
#define CONV_BLOCKS (NUM_MOVIES_N * FEAT / (256 * 8))   // 6250
__global__ __launch_bounds__(256) void prep_all(
    const float* __restrict__ t, __hip_bfloat16* __restrict__ tb,
    const float* __restrict__ Wu, const float* __restrict__ Wm,
    const float* __restrict__ W1, const float* __restrict__ W2,
    const float* __restrict__ bu, const float* __restrict__ bm,
    __hip_bfloat16* __restrict__ WcatT, __hip_bfloat16* __restrict__ WmT,
    __hip_bfloat16* __restrict__ W1T,  __hip_bfloat16* __restrict__ W2T,
    float* __restrict__ bc) {
  int bid = blockIdx.x;
  if (bid < CONV_BLOCKS) {
    size_t i = ((size_t)bid * 256 + threadIdx.x) * 8;
    float4 v0 = *(const float4*)(t + i);
    float4 v1 = *(const float4*)(t + i + 4);
    __hip_bfloat16 o[8];
    o[0] = f2bf(v0.x); o[1] = f2bf(v0.y); o[2] = f2bf(v0.z); o[3] = f2bf(v0.w);
    o[4] = f2bf(v1.x); o[5] = f2bf(v1.y); o[6] = f2bf(v1.z); o[7] = f2bf(v1.w);
    *(short8*)(tb + i) = *(short8*)o;
  } else {
    int idx = (bid - CONV_BLOCKS) * 256 + threadIdx.x;   // 0..65535
    int n = idx & 255, k = idx >> 8;
    float v = (k < 128) ? Wu[k * 256 + n] : Wm[(k - 128) * 256 + n];
    WcatT[n * 256 + k] = f2bf(v);
    W1T[n * 256 + k]   = f2bf(W1[k * 256 + n]);
    if (k < 128) WmT[n * 128 + k] = f2bf(Wm[k * 256 + n]);
    if (idx < 32768) {
      int k2 = idx >> 7, n2 = idx & 127;
      W2T[n2 * 256 + k2] = f2bf(W2[k2 * 128 + n2]);
    }
    if (idx < 256) bc[idx] = bu[idx] + bm[idx];
  }
}

// ---------------------------------------------------------------------------
// gather_user: one WAVE per batch row. Lane slice = 16 B; quad q handles
// nbr 4*it+q -> 13 wave-loads of 1 KB. Cross-quad shfl_xor reduce.
// ---------------------------------------------------------------------------
__global__ __launch_bounds__(256) void gather_user(
    const float* __restrict__ users, const int* __restrict__ nbr_ids,
    const __hip_bfloat16* __restrict__ tb, __hip_bfloat16* __restrict__ A_user) {
  int row  = (blockIdx.x << 2) + (threadIdx.x >> 6);
  int lane = threadIdx.x & 63;
  int quad = lane >> 4, sl = lane & 15;
  const int* nb = nbr_ids + row * NNBR;
  float acc[8] = {0.f, 0.f, 0.f, 0.f, 0.f, 0.f, 0.f, 0.f};
  #pragma unroll
  for (int it = 0; it < 13; ++it) {
    int j = it * 4 + quad;
    if (j < NNBR) {
      int id = nb[j];
      short8 v = *(const short8*)(tb + (size_t)id * FEAT + sl * 8);
      #pragma unroll
      for (int e = 0; e < 8; ++e) acc[e] += bfb2f(v[e]);
    }
  }
  __hip_bfloat16 o[8];
  #pragma unroll
  for (int e = 0; e < 8; ++e) {
    float v = acc[e];
    v += __shfl_xor(v, 16, 64);
    v += __shfl_xor(v, 32, 64);
    o[e] = f2bf(v * (1.f / NNBR));
  }
  if (quad == 0)
    *(short8*)(A_user + (size_t)row * 256 + 128 + sl * 8) = *(short8*)o;
  float2 uv = ((const float2*)(users + (size_t)row * FEAT))[lane];
  __hip_bfloat162 t0; t0.x = f2bf(uv.x); t0.y = f2bf(uv.y);
  ((__hip_bfloat162*)(A_user + (size_t)row * 256))[lane] = t0;
}

// ---------------------------------------------------------------------------
// layer: one GEMM layer on a 64-row LDS tile.
//
// R11 lesson (three strikes: R6/R8/R11): LLVM will not keep >~32 VGPRs of
// loop-invariant global loads resident across an unrolled loop — B re-read
// per it-iter put ~950 MB through L2 (the measured 43-us wall). Restructure
// j-OUTER / it-INNER: per 16-col j-tile B is only KK short8 = 32 VGPRs
// (footprint ~100, fits ANY occupancy target, so no pressure-sinking), and
// A-frags are re-read from LDS per (j,it) — m97's proven 8-ds_read:16-MFMA
// ratio on the pipe the compiler schedules with fine-grained lgkmcnt.
// B L2 traffic: ~950 MB -> ~240 MB (once per j instead of once per (j,it)).
// ---------------------------------------------------------------------------
template <int K0, int NCOL, bool RELU, bool TOGLB>
__device__ __forceinline__ void layer(
    const __hip_bfloat16* Ain,
    const __hip_bfloat16* __restrict__ Wt, const float* __restrict__ bias,
    __hip_bfloat16* Olds, float* __restrict__ Oglb,
    int wid, int quad, int lrow) {
  constexpr int KK = K0 / 32;
  constexpr int JN = NCOL / 128;         // 16-col j-tiles per wave (2 or 1)
  const int c0 = wid * JN * 16;

  #pragma unroll
  for (int j = 0; j < JN; ++j) {
    const int col = c0 + j * 16 + lrow;
    short8 bfr[KK];                      // 32 VGPRs — survives hoisting
    #pragma unroll
    for (int kc = 0; kc < KK; ++kc)
      bfr[kc] = *(const short8*)(Wt + (size_t)col * K0 + kc * 32 + quad * 8);
    const float bv = bias[col];

    #pragma unroll
    for (int it = 0; it < 4; ++it) {
      int r = it * 16 + lrow;
      short8 af[KK];
      #pragma unroll
      for (int kc = 0; kc < KK; ++kc)
        af[kc] = *(const short8*)&Ain[r * K0 +
                                      (((kc * 4 + quad) ^ (r & 7)) << 3)];
      floatx4 pa = {}, pb = {};
      #pragma unroll
      for (int kc = 0; kc < KK; kc += 2) {
        pa = mfma16(af[kc],     bfr[kc],     pa);
        pb = mfma16(af[kc + 1], bfr[kc + 1], pb);
      }
      floatx4 a = pa + pb;
      #pragma unroll
      for (int rr = 0; rr < 4; ++rr) {
        int row = it * 16 + quad * 4 + rr;
        float v = a[rr] + bv;
        if (RELU) v = fmaxf(v, 0.f);
        if (TOGLB) {
          Oglb[(size_t)row * NCOL + col] = v;
        } else {
          int ch = col >> 3;
          Olds[row * 256 + (((ch ^ (row & 7)) << 3) | (col & 7))] = f2bf(v);
        }
      }
    }
  }
}

// ---------------------------------------------------------------------------
// fused_mlp: one block = 64 rows of stream s (0 user / 1 pos / 2 neg),
// all 3 layers; A/E/H in LDS (64 KB), B in small per-j register tiles.
// 3 barriers per block. __launch_bounds__(512,4): VGPR cap 128 (footprint
// ~100 fits) and LDS 64 KB -> 2 blocks/CU co-resident, so block-level TLP
// hides the A-stage drain and per-j B-load bursts.
// ---------------------------------------------------------------------------
__global__ __launch_bounds__(512, 4) void fused_mlp(
    const __hip_bfloat16* __restrict__ A_user,
    const __hip_bfloat16* __restrict__ tb,
    const int* __restrict__ pos_ids, const int* __restrict__ neg_ids,
    const __hip_bfloat16* __restrict__ WcatT,
    const __hip_bfloat16* __restrict__ WmT,
    const __hip_bfloat16* __restrict__ W1T,
    const __hip_bfloat16* __restrict__ W2T,
    const float* __restrict__ bc, const float* __restrict__ bmv,
    const float* __restrict__ b1, const float* __restrict__ b2,
    float* __restrict__ out) {
  __shared__ __hip_bfloat16 A_lds[64 * 256];   // 32 KB: A, then H
  __shared__ __hip_bfloat16 E_lds[64 * 256];   // 32 KB: E

  const int t    = threadIdx.x;
  const int lane = t & 63, wid = t >> 6;       // wid 0..7
  const int quad = lane >> 4, lrow = lane & 15;
  const int s    = blockIdx.x % 3;
  const long m0  = (long)(blockIdx.x / 3) * 64;

  // ---- stage A tile (async DMA; drained by the first barrier) ----
  if (s == 0) {
    #pragma unroll
    for (int i = 0; i < 4; ++i) {
      int c = t + i * 512;                     // 2048 slots: r=c>>5, sl=c&31
      int r = c >> 5, sl = c & 31;
      gld16(A_user + ((size_t)(m0 + r) << 8) + ((sl ^ (r & 7)) << 3),
            A_lds + (c << 3));
    }
  } else {
    const int* ids = (s == 1) ? pos_ids : neg_ids;
    #pragma unroll
    for (int i = 0; i < 2; ++i) {
      int c = t + i * 512;                     // 1024 slots: r=c>>4, sl=c&15
      int r = c >> 4, sl = c & 15;
      int id = ids[m0 + r];
      gld16(tb + ((size_t)id << 7) + ((sl ^ (r & 7)) << 3),
            A_lds + (c << 3));
    }
  }
  __syncthreads();                             // A staged (vmcnt(0) drain)

  // ---- layer 0 -> E_lds (no relu) ----
  if (s == 0)
    layer<256, 256, false, false>(A_lds, WcatT, bc, E_lds, nullptr,
                                  wid, quad, lrow);
  else
    layer<128, 256, false, false>(A_lds, WmT, bmv, E_lds, nullptr,
                                  wid, quad, lrow);
  __syncthreads();                             // E complete (A reads done)

  // ---- layer 1: H = relu(E @ W1^T + b1) -> A_lds ----
  layer<256, 256, true, false>(E_lds, W1T, b1, A_lds, nullptr,
                               wid, quad, lrow);
  __syncthreads();                             // H complete

  // ---- layer 2: out = relu(H @ W2^T + b2) -> global fp32 ----
  layer<256, 128, true, true>(A_lds, W2T, b2, nullptr,
                              out + ((size_t)s * BATCH_N + m0) * 128,
                              wid, quad, lrow);
}

// ---------------------------------------------------------------------------
extern "C" void kernel_launch(void* const* d_in, const int* in_sizes, int n_in,
                              void* d_out, int out_size, void* d_ws, size_t ws_size,
                              hipStream_t stream) {
  const float* users   = (const float*)d_in[0];
  // d_in[1] pos_movies, d_in[2] neg_movies, d_in[3] user_ids: unused by ref
  const int*   pos_ids = (const int*)d_in[4];
  const int*   neg_ids = (const int*)d_in[5];
  const int*   nbr_ids = (const int*)d_in[6];
  const float* table   = (const float*)d_in[7];
  const float* Wu = (const float*)d_in[8];
  const float* bu = (const float*)d_in[9];
  const float* Wm = (const float*)d_in[10];
  const float* bm = (const float*)d_in[11];
  const float* W1 = (const float*)d_in[12];
  const float* b1 = (const float*)d_in[13];
  const float* W2 = (const float*)d_in[14];
  const float* b2 = (const float*)d_in[15];
  float* out = (float*)d_out;

  // workspace carve (all 256B aligned). Total ~34 MB.
  char* p = (char*)d_ws;
  auto carve = [&](size_t bytes) { char* r = p; p += (bytes + 255) & ~(size_t)255; return r; };
  __hip_bfloat16* tb     = (__hip_bfloat16*)carve((size_t)NUM_MOVIES_N * FEAT * 2);
  __hip_bfloat16* WcatT  = (__hip_bfloat16*)carve(256 * 256 * 2);
  __hip_bfloat16* WmT    = (__hip_bfloat16*)carve(256 * 128 * 2);
  __hip_bfloat16* W1T    = (__hip_bfloat16*)carve(256 * 256 * 2);
  __hip_bfloat16* W2T    = (__hip_bfloat16*)carve(128 * 256 * 2);
  float*          bc     = (float*)carve(256 * 4);
  __hip_bfloat16* A_user = (__hip_bfloat16*)carve((size_t)BATCH_N * 256 * 2);

  prep_all<<<CONV_BLOCKS + 256, 256, 0, stream>>>(
      table, tb, Wu, Wm, W1, W2, bu, bm, WcatT, WmT, W1T, W2T, bc);
  gather_user<<<BATCH_N / 4, 256, 0, stream>>>(users, nbr_ids, tb, A_user);
  fused_mlp<<<3 * BATCH_N / 64, 512, 0, stream>>>(
      A_user, tb, pos_ids, neg_ids, WcatT, WmT, W1T, W2T,
      bc, bm, b1, b2, out);
}